// Round 16
// baseline (61.207 us; speedup 1.0000x reference)
//
#include <hip/hip_runtime.h>
#include <math.h>

// out[b,o] = min_i(W[o,i]+X[b,i]) + max_i(W[o,i]+X[b,i])
// B=1024, OUT=1024, IN=512, fp32.
//
// R16 = R15 structure with PURE-C compute (no inline asm).
// R15 post-mortem: asm "+v" on a 128-element accumulator that the
// allocator put in AGPRs forced v_accvgpr shuttles around every min3/max3
// (~2 extra VALU each) -> main kernel 42us vs 20 modeled. fminf/fmaxf
// chains fuse to v_min3/v_max3 anyway (R4/R5 evidence), and pure C lets
// the compiler consume AGPR operands directly (gfx950 unified file).
//  - 8x8 per-lane micro over 64x64 tile; k-paired quads; f2 adds
//    (v_pk_add_f32): VALU ~9.8us + DS reads ~9.8us + staging ~2.6us.
//  - K-split x2 via blockIdx.z -> 512 blocks of 256thr (2/CU, proven
//    dispatch shape); partials to d_ws; combine kernel finishes.
//  - LDS: quad (q,im) at byte kp*512 + q*128 + im*16 -> conflict-free
//    b128 reads. Wave-private dbuf, zero main-loop barriers.

typedef float f4 __attribute__((ext_vector_type(4)));
typedef float f2 __attribute__((ext_vector_type(2)));

constexpr int B_DIM  = 1024;
constexpr int O_DIM  = 1024;
constexpr int IN_DIM = 512;
constexpr int TILE   = 64;
constexpr int P      = B_DIM * O_DIM;   // 1M outputs

template <int KSPLIT>
__global__ __launch_bounds__(256) void tropical_gemm(
    const float* __restrict__ X, const float* __restrict__ W,
    float* __restrict__ out, float* __restrict__ ws) {
    constexpr int KW     = (KSPLIT == 2) ? 64 : 128;  // k per wave
    constexpr int NSTAGE = KW / 8;
    __shared__ float lds[16384];   // 64 KB: loop 4x2048 fl; merge 2x8192 fl

    const int tid  = threadIdx.x;
    const int w    = tid >> 6;
    const int lane = tid & 63;
    const int im   = lane >> 3;    // row-block 0..7
    const int in_  = lane & 7;     // col-block 0..7
    const int b0   = blockIdx.y * TILE;
    const int o0   = blockIdx.x * TILE;
    const int kh   = (KSPLIT == 2) ? blockIdx.z : 0;
    const int kbase = kh * (IN_DIM / KSPLIT) + w * KW;

    const float* Xp = X + (size_t)(b0 + lane) * IN_DIM + kbase;
    const float* Wp = W + (size_t)(o0 + lane) * IN_DIM + kbase;

    float* wbase = &lds[w * 2048];   // wave-private 8 KB (2 buf x 1024 fl)
    // staging f2 slot for row/col r=lane (float offset within buffer):
    const int stw = ((lane & 7) >> 1) * 32 + (lane >> 3) * 4 + (lane & 1) * 2;

    float mn[8][8], mx[8][8];
#pragma unroll
    for (int i = 0; i < 8; ++i)
#pragma unroll
        for (int j = 0; j < 8; ++j) { mn[i][j] = INFINITY; mx[i][j] = -INFINITY; }

#define PF(S)                                                                 \
    do {                                                                      \
        xa = *(const f4*)(Xp + (S) * 8);                                      \
        xb = *(const f4*)(Xp + (S) * 8 + 4);                                  \
        wa = *(const f4*)(Wp + (S) * 8);                                      \
        wb = *(const f4*)(Wp + (S) * 8 + 4);                                  \
    } while (0)

#define STAGE(BUF)                                                            \
    do {                                                                      \
        float* dX_ = wbase + (BUF) * 1024;                                    \
        float* dW_ = dX_ + 512;                                               \
        f2 x0_ = {xa[0], xa[1]}, x1_ = {xa[2], xa[3]};                        \
        f2 x2_ = {xb[0], xb[1]}, x3_ = {xb[2], xb[3]};                        \
        f2 w0_ = {wa[0], wa[1]}, w1_ = {wa[2], wa[3]};                        \
        f2 w2_ = {wb[0], wb[1]}, w3_ = {wb[2], wb[3]};                        \
        *(f2*)(dX_ + 0 * 128 + stw) = x0_;                                    \
        *(f2*)(dX_ + 1 * 128 + stw) = x1_;                                    \
        *(f2*)(dX_ + 2 * 128 + stw) = x2_;                                    \
        *(f2*)(dX_ + 3 * 128 + stw) = x3_;                                    \
        *(f2*)(dW_ + 0 * 128 + stw) = w0_;                                    \
        *(f2*)(dW_ + 1 * 128 + stw) = w1_;                                    \
        *(f2*)(dW_ + 2 * 128 + stw) = w2_;                                    \
        *(f2*)(dW_ + 3 * 128 + stw) = w3_;                                    \
    } while (0)

    // one k-pair: 8 b128 reads, pure-C pk_add + min3/max3 (compiler-fused)
#define KPBODY(KP, SX, SW)                                                    \
    do {                                                                      \
        f4 xq0 = *(const f4*)((SX) + (KP) * 128 + 0 * 32 + im * 4);           \
        f4 xq1 = *(const f4*)((SX) + (KP) * 128 + 1 * 32 + im * 4);           \
        f4 xq2 = *(const f4*)((SX) + (KP) * 128 + 2 * 32 + im * 4);           \
        f4 xq3 = *(const f4*)((SX) + (KP) * 128 + 3 * 32 + im * 4);           \
        f4 wq0 = *(const f4*)((SW) + (KP) * 128 + 0 * 32 + in_ * 4);          \
        f4 wq1 = *(const f4*)((SW) + (KP) * 128 + 1 * 32 + in_ * 4);          \
        f4 wq2 = *(const f4*)((SW) + (KP) * 128 + 2 * 32 + in_ * 4);          \
        f4 wq3 = *(const f4*)((SW) + (KP) * 128 + 3 * 32 + in_ * 4);          \
        f4 xq[4] = {xq0, xq1, xq2, xq3};                                      \
        f4 wq[4] = {wq0, wq1, wq2, wq3};                                      \
        _Pragma("unroll")                                                     \
        for (int q_ = 0; q_ < 4; ++q_) {                                      \
            f2 xl_ = {xq[q_][0], xq[q_][1]};                                  \
            f2 xh_ = {xq[q_][2], xq[q_][3]};                                  \
            _Pragma("unroll")                                                 \
            for (int p_ = 0; p_ < 4; ++p_) {                                  \
                f2 wl_  = {wq[p_][0], wq[p_][1]};                             \
                f2 wh_  = {wq[p_][2], wq[p_][3]};                             \
                f2 s00_ = xl_ + wl_;                                          \
                f2 s01_ = xl_ + wh_;                                          \
                f2 s10_ = xh_ + wl_;                                          \
                f2 s11_ = xh_ + wh_;                                          \
                mn[2*q_  ][2*p_  ] = fminf(mn[2*q_  ][2*p_  ], fminf(s00_[0], s00_[1])); \
                mx[2*q_  ][2*p_  ] = fmaxf(mx[2*q_  ][2*p_  ], fmaxf(s00_[0], s00_[1])); \
                mn[2*q_  ][2*p_+1] = fminf(mn[2*q_  ][2*p_+1], fminf(s01_[0], s01_[1])); \
                mx[2*q_  ][2*p_+1] = fmaxf(mx[2*q_  ][2*p_+1], fmaxf(s01_[0], s01_[1])); \
                mn[2*q_+1][2*p_  ] = fminf(mn[2*q_+1][2*p_  ], fminf(s10_[0], s10_[1])); \
                mx[2*q_+1][2*p_  ] = fmaxf(mx[2*q_+1][2*p_  ], fmaxf(s10_[0], s10_[1])); \
                mn[2*q_+1][2*p_+1] = fminf(mn[2*q_+1][2*p_+1], fminf(s11_[0], s11_[1])); \
                mx[2*q_+1][2*p_+1] = fmaxf(mx[2*q_+1][2*p_+1], fmaxf(s11_[0], s11_[1])); \
            }                                                                 \
        }                                                                     \
    } while (0)

    // ---- main loop (wave-private, no barriers) ----
    f4 xa, xb, wa, wb;
    PF(0);
    STAGE(0);
    PF(1);

#pragma unroll 1
    for (int s = 0; s < NSTAGE; ++s) {
        const float* sX = wbase + (s & 1) * 1024;
        const float* sW = sX + 512;
        KPBODY(0, sX, sW);
        KPBODY(1, sX, sW);
        if (s + 1 < NSTAGE) {
            STAGE((s + 1) & 1);         // from globals prefetched last iter
            if (s + 2 < NSTAGE) PF(s + 2);
        }
        KPBODY(2, sX, sW);
        KPBODY(3, sX, sW);
    }
#undef PF
#undef STAGE
#undef KPBODY

    // ---- merge 4 wave partials: 2-round tree, 32 KB slots ----
#define DUMP_STATE(SL)                                                        \
    do {                                                                      \
        float* p_ = lds + (SL) * 8192 + lane * 4;                             \
        _Pragma("unroll")                                                     \
        for (int r_ = 0; r_ < 8; ++r_) {                                      \
            f4 a_ = {mn[r_][0], mn[r_][1], mn[r_][2], mn[r_][3]};             \
            f4 b_ = {mn[r_][4], mn[r_][5], mn[r_][6], mn[r_][7]};             \
            f4 c_ = {mx[r_][0], mx[r_][1], mx[r_][2], mx[r_][3]};             \
            f4 d_ = {mx[r_][4], mx[r_][5], mx[r_][6], mx[r_][7]};             \
            *(f4*)(p_ + (2 * r_) * 256)      = a_;                            \
            *(f4*)(p_ + (2 * r_ + 1) * 256)  = b_;                            \
            *(f4*)(p_ + (16 + 2 * r_) * 256) = c_;                            \
            *(f4*)(p_ + (17 + 2 * r_) * 256) = d_;                            \
        }                                                                     \
    } while (0)

#define MERGE_STATE(SL)                                                       \
    do {                                                                      \
        const float* p_ = lds + (SL) * 8192 + lane * 4;                       \
        _Pragma("unroll")                                                     \
        for (int r_ = 0; r_ < 8; ++r_) {                                      \
            f4 a_ = *(const f4*)(p_ + (2 * r_) * 256);                        \
            f4 b_ = *(const f4*)(p_ + (2 * r_ + 1) * 256);                    \
            f4 c_ = *(const f4*)(p_ + (16 + 2 * r_) * 256);                   \
            f4 d_ = *(const f4*)(p_ + (17 + 2 * r_) * 256);                   \
            _Pragma("unroll")                                                 \
            for (int j_ = 0; j_ < 4; ++j_) {                                  \
                mn[r_][j_]     = fminf(mn[r_][j_],     a_[j_]);               \
                mn[r_][4 + j_] = fminf(mn[r_][4 + j_], b_[j_]);               \
                mx[r_][j_]     = fmaxf(mx[r_][j_],     c_[j_]);               \
                mx[r_][4 + j_] = fmaxf(mx[r_][4 + j_], d_[j_]);               \
            }                                                                 \
        }                                                                     \
    } while (0)

    __syncthreads();
    if (w == 2) DUMP_STATE(0);
    if (w == 3) DUMP_STATE(1);
    __syncthreads();
    if (w == 0) MERGE_STATE(0);
    if (w == 1) MERGE_STATE(1);
    __syncthreads();
    if (w == 1) DUMP_STATE(0);
    __syncthreads();
    if (w == 0) {
        MERGE_STATE(0);
        if (KSPLIT == 2) {
            float* mnp = ws + (size_t)kh * 2 * P;
            float* mxp = mnp + P;
#pragma unroll
            for (int r = 0; r < 8; ++r) {
                const size_t off = (size_t)(b0 + im * 8 + r) * O_DIM + o0 + in_ * 8;
                f4 a = {mn[r][0], mn[r][1], mn[r][2], mn[r][3]};
                f4 b = {mn[r][4], mn[r][5], mn[r][6], mn[r][7]};
                f4 c = {mx[r][0], mx[r][1], mx[r][2], mx[r][3]};
                f4 d = {mx[r][4], mx[r][5], mx[r][6], mx[r][7]};
                *(f4*)(mnp + off)     = a;
                *(f4*)(mnp + off + 4) = b;
                *(f4*)(mxp + off)     = c;
                *(f4*)(mxp + off + 4) = d;
            }
        } else {
            float* op = out + (size_t)(b0 + im * 8) * O_DIM + o0 + in_ * 8;
#pragma unroll
            for (int r = 0; r < 8; ++r) {
                f4 v0 = {mn[r][0] + mx[r][0], mn[r][1] + mx[r][1],
                         mn[r][2] + mx[r][2], mn[r][3] + mx[r][3]};
                f4 v1 = {mn[r][4] + mx[r][4], mn[r][5] + mx[r][5],
                         mn[r][6] + mx[r][6], mn[r][7] + mx[r][7]};
                *(f4*)(op + (size_t)r * O_DIM)     = v0;
                *(f4*)(op + (size_t)r * O_DIM + 4) = v1;
            }
        }
    }
#undef DUMP_STATE
#undef MERGE_STATE
}

// out = min(mn0, mn1) + max(mx0, mx1); 1 f4 per thread, grid 1024x256.
__global__ __launch_bounds__(256) void combine_k(
    const float* __restrict__ ws, float* __restrict__ out) {
    const int i = (blockIdx.x * 256 + threadIdx.x) * 4;
    f4 a = *(const f4*)(ws + i);              // mn kh0
    f4 b = *(const f4*)(ws + 2 * P + i);      // mn kh1
    f4 c = *(const f4*)(ws + P + i);          // mx kh0
    f4 d = *(const f4*)(ws + 3 * P + i);      // mx kh1
    f4 r;
#pragma unroll
    for (int j = 0; j < 4; ++j) r[j] = fminf(a[j], b[j]) + fmaxf(c[j], d[j]);
    *(f4*)(out + i) = r;
}

extern "C" void kernel_launch(void* const* d_in, const int* in_sizes, int n_in,
                              void* d_out, int out_size, void* d_ws, size_t ws_size,
                              hipStream_t stream) {
    (void)in_sizes; (void)n_in; (void)out_size;
    const float* X = (const float*)d_in[0];
    const float* W = (const float*)d_in[1];
    float* out     = (float*)d_out;

    const size_t need = (size_t)4 * P * sizeof(float);   // 16 MB partials
    if (ws_size >= need) {
        tropical_gemm<2><<<dim3(16, 16, 2), dim3(256), 0, stream>>>(
            X, W, out, (float*)d_ws);
        combine_k<<<dim3(1024), dim3(256), 0, stream>>>((const float*)d_ws, out);
    } else {
        tropical_gemm<1><<<dim3(16, 16, 1), dim3(256), 0, stream>>>(
            X, W, out, nullptr);
    }
}

// Round 18
// 38.297 us; speedup vs baseline: 1.5982x; 1.5982x over previous
//
#include <hip/hip_runtime.h>
#include <math.h>

// out[b,o] = min_i(W[o,i]+X[b,i]) + max_i(W[o,i]+X[b,i])
// B=1024, OUT=1024, IN=512, fp32 in/out.
//
// R18 = R17 with the shufflevector compile error fixed: b128 fragments load
// into a 16B-aligned struct of 4 named h2s; unrolled .h[i] indexing keeps
// each h2 a separate 32-bit register (v_pk_* operand), no shuffles needed.
// Theory unchanged: packed f16 compute (pk_add+pk_min+pk_max = 1.5
// VALU/triple ~10.2us) + halved LDS bytes (reads ~7.7us, writes ~1.9us)
// on the R6 geometry. Error ~0.01 << 4.53e-2 threshold.
// Tile 64x32, 256thr/4 waves, wave-private k-slice 128, dbuf LDS 3KB/wave,
// zero main-loop barriers, 2-round f32 merge tree, 512 blocks = 2/CU.

typedef float f4 __attribute__((ext_vector_type(4)));
typedef _Float16 h2 __attribute__((ext_vector_type(2)));

struct __attribute__((aligned(16))) h2x4 { h2 h[4]; };

constexpr int B_DIM  = 1024;
constexpr int O_DIM  = 1024;
constexpr int IN_DIM = 512;

constexpr int TM     = 64;           // batch-tile
constexpr int TN     = 32;           // out-tile
constexpr int KW     = 128;          // k per wave (512 / 4 waves)
constexpr int BK     = 8;            // k per stage (4 k-pairs)
constexpr int NSTAGE = KW / BK;      // 16

__global__ __launch_bounds__(256) void tropical_gemm(
    const float* __restrict__ X, const float* __restrict__ W,
    float* __restrict__ out) {
    __shared__ float lds[8192];   // 32 KB: loop 4 waves x 3072 B; merge 2x16KB

    const int tid  = threadIdx.x;
    const int w    = tid >> 6;     // wave 0..3
    const int lane = tid & 63;
    const int im   = lane >> 3;    // micro-row block 0..7 (8 X rows)
    const int in_  = lane & 7;     // micro-col block 0..7 (4 W cols)
    const int b0   = blockIdx.y * TM;
    const int o0   = blockIdx.x * TN;
    const int wrow = lane >> 1;    // W staging: 2 lanes per o-row
    const int wsel = lane & 1;     // which 4-k half of the row's 8

    const float* Xp = X + (size_t)(b0 + lane) * IN_DIM + w * KW;
    const float* Wp = W + (size_t)(o0 + wrow) * IN_DIM + w * KW + wsel * 4;

    // wave-private LDS: 2 buffers x (X 1024 B [4 kp rows x 64 h2] |
    //                                W  512 B [4 kp rows x 32 h2])
    char* wbase = (char*)lds + w * 3072;

    h2 mn2[8][4], mx2[8][4];
    {
        const h2 pinf = {(_Float16)INFINITY, (_Float16)INFINITY};
        const h2 ninf = {(_Float16)(-INFINITY), (_Float16)(-INFINITY)};
#pragma unroll
        for (int i = 0; i < 8; ++i)
#pragma unroll
            for (int j = 0; j < 4; ++j) { mn2[i][j] = pinf; mx2[i][j] = ninf; }
    }

#define PF(S)                                                                 \
    do {                                                                      \
        xa = *(const f4*)(Xp + (S) * BK);                                     \
        xb = *(const f4*)(Xp + (S) * BK + 4);                                 \
        wv = *(const f4*)(Wp + (S) * BK);                                     \
    } while (0)

    // convert + stage one 8k chunk: 4 X h2 writes + 2 W h2 writes
#define STAGE(BUF)                                                            \
    do {                                                                      \
        char* dX_ = wbase + (BUF) * 1536;                                     \
        char* dW_ = dX_ + 1024;                                               \
        h2 p0_ = {(_Float16)xa[0], (_Float16)xa[1]};                          \
        h2 p1_ = {(_Float16)xa[2], (_Float16)xa[3]};                          \
        h2 p2_ = {(_Float16)xb[0], (_Float16)xb[1]};                          \
        h2 p3_ = {(_Float16)xb[2], (_Float16)xb[3]};                          \
        h2 q0_ = {(_Float16)wv[0], (_Float16)wv[1]};                          \
        h2 q1_ = {(_Float16)wv[2], (_Float16)wv[3]};                          \
        *(h2*)(dX_ + 0 * 256 + lane * 4) = p0_;                               \
        *(h2*)(dX_ + 1 * 256 + lane * 4) = p1_;                               \
        *(h2*)(dX_ + 2 * 256 + lane * 4) = p2_;                               \
        *(h2*)(dX_ + 3 * 256 + lane * 4) = p3_;                               \
        *(h2*)(dW_ + (wsel * 2 + 0) * 128 + wrow * 4) = q0_;                  \
        *(h2*)(dW_ + (wsel * 2 + 1) * 128 + wrow * 4) = q1_;                  \
    } while (0)

    // load one k-pair's fragments: 2 X b128 (rows im*8..+7) + 1 W b128
#define LOADQ(P, SX, SW, KP)                                                  \
    do {                                                                      \
        P##xl = *(const h2x4*)((SX) + (KP) * 256 + im * 32);                  \
        P##xh = *(const h2x4*)((SX) + (KP) * 256 + im * 32 + 16);             \
        P##wq = *(const h2x4*)((SW) + (KP) * 128 + in_ * 16);                 \
    } while (0)

    // 32 (a,b) pairs x 2 k: pk_add + pk_min + pk_max each
#define COMPUTE(P)                                                            \
    do {                                                                      \
        _Pragma("unroll")                                                     \
        for (int a_ = 0; a_ < 8; ++a_) {                                      \
            h2 xv_ = (a_ < 4) ? P##xl.h[a_ & 3] : P##xh.h[a_ & 3];            \
            _Pragma("unroll")                                                 \
            for (int b_ = 0; b_ < 4; ++b_) {                                  \
                h2 s_ = xv_ + P##wq.h[b_];                                    \
                mn2[a_][b_] = __builtin_elementwise_min(mn2[a_][b_], s_);     \
                mx2[a_][b_] = __builtin_elementwise_max(mx2[a_][b_], s_);     \
            }                                                                 \
        }                                                                     \
    } while (0)

    // ---- prologue ----
    f4 xa, xb, wv;
    PF(0);
    STAGE(0);
    PF(1);

    h2x4 Axl, Axh, Awq;
    h2x4 Bxl, Bxh, Bwq;

#pragma unroll 1
    for (int s = 0; s < NSTAGE; ++s) {
        const char* sX = wbase + (s & 1) * 1536;
        const char* sW = sX + 1024;

        LOADQ(A, sX, sW, 0);
        LOADQ(B, sX, sW, 1);
        COMPUTE(A);
        LOADQ(A, sX, sW, 2);
        COMPUTE(B);
        LOADQ(B, sX, sW, 3);
        COMPUTE(A);
        if (s + 1 < NSTAGE) {
            STAGE((s + 1) & 1);       // from globals prefetched last iter
            if (s + 2 < NSTAGE) PF(s + 2);
        }
        COMPUTE(B);
    }
#undef PF
#undef STAGE
#undef LOADQ
#undef COMPUTE

    // ---- unpack packed k-lanes to f32 ----
    float mn[8][4], mx[8][4];
#pragma unroll
    for (int r = 0; r < 8; ++r)
#pragma unroll
        for (int c = 0; c < 4; ++c) {
            mn[r][c] = fminf((float)mn2[r][c][0], (float)mn2[r][c][1]);
            mx[r][c] = fmaxf((float)mx2[r][c][0], (float)mx2[r][c][1]);
        }

    // ---- merge 4 wave partials: 2-round LDS tree (R6 verbatim) ----
#define DUMP_STATE(slotbase)                                                  \
    do {                                                                      \
        float* p_ = (slotbase) + lane * 4;                                    \
        _Pragma("unroll")                                                     \
        for (int r_ = 0; r_ < 8; ++r_) {                                      \
            *(float4*)(p_ + r_ * 256) =                                       \
                make_float4(mn[r_][0], mn[r_][1], mn[r_][2], mn[r_][3]);      \
            *(float4*)(p_ + (8 + r_) * 256) =                                 \
                make_float4(mx[r_][0], mx[r_][1], mx[r_][2], mx[r_][3]);      \
        }                                                                     \
    } while (0)

#define MERGE_STATE(slotbase)                                                 \
    do {                                                                      \
        const float* p_ = (slotbase) + lane * 4;                              \
        _Pragma("unroll")                                                     \
        for (int r_ = 0; r_ < 8; ++r_) {                                      \
            float4 vn_ = *(const float4*)(p_ + r_ * 256);                     \
            float4 vx_ = *(const float4*)(p_ + (8 + r_) * 256);               \
            mn[r_][0] = fminf(mn[r_][0], vn_.x);                              \
            mn[r_][1] = fminf(mn[r_][1], vn_.y);                              \
            mn[r_][2] = fminf(mn[r_][2], vn_.z);                              \
            mn[r_][3] = fminf(mn[r_][3], vn_.w);                              \
            mx[r_][0] = fmaxf(mx[r_][0], vx_.x);                              \
            mx[r_][1] = fmaxf(mx[r_][1], vx_.y);                              \
            mx[r_][2] = fmaxf(mx[r_][2], vx_.z);                              \
            mx[r_][3] = fmaxf(mx[r_][3], vx_.w);                              \
        }                                                                     \
    } while (0)

    float* slotA = lds;           // 4096 floats
    float* slotB = lds + 4096;

    __syncthreads();
    if (w == 2) DUMP_STATE(slotA);
    if (w == 3) DUMP_STATE(slotB);
    __syncthreads();
    if (w == 0) MERGE_STATE(slotA);   // w0 <- {w0,w2}
    if (w == 1) MERGE_STATE(slotB);   // w1 <- {w1,w3}
    __syncthreads();
    if (w == 1) DUMP_STATE(slotA);
    __syncthreads();
    if (w == 0) {
        MERGE_STATE(slotA);           // w0 <- all
        float* op = out + (size_t)(b0 + im * 8) * O_DIM + o0 + in_ * 4;
#pragma unroll
        for (int r = 0; r < 8; ++r)
            *(float4*)(op + (size_t)r * O_DIM) =
                make_float4(mn[r][0] + mx[r][0], mn[r][1] + mx[r][1],
                            mn[r][2] + mx[r][2], mn[r][3] + mx[r][3]);
    }
#undef DUMP_STATE
#undef MERGE_STATE
}

extern "C" void kernel_launch(void* const* d_in, const int* in_sizes, int n_in,
                              void* d_out, int out_size, void* d_ws, size_t ws_size,
                              hipStream_t stream) {
    (void)in_sizes; (void)n_in; (void)d_ws; (void)ws_size; (void)out_size;
    const float* X = (const float*)d_in[0];
    const float* W = (const float*)d_in[1];
    float* out     = (float*)d_out;

    dim3 grid(O_DIM / TN, B_DIM / TM);  // (32, 16) = 512 blocks = 2/CU
    tropical_gemm<<<grid, dim3(256), 0, stream>>>(X, W, out);
}